// Round 4
// baseline (67.516 us; speedup 1.0000x reference)
//
#include <hip/hip_runtime.h>
#include <hip/hip_bf16.h>
#include <math.h>

#define S_LEN 2048
#define B_SZ  32
#define DIM   1024   // D == E == H == 1024
#define PTR   9      // min((0 + 9) * 1, 2047)
#define EPSV  1e-8f
#define NEGINF -1e9f
#define MROWS 320    // 32 dec rows + 288 enc rows
#define GRID  256

typedef __attribute__((ext_vector_type(8)))  short  short8;
typedef __attribute__((ext_vector_type(16))) float  f32x16;

__device__ __forceinline__ ushort f2bf(float x) {
    __hip_bfloat16 h = __float2bfloat16(x);   // RNE
    return *(ushort*)&h;
}

__device__ __forceinline__ float fast_tanh(float x) {
    float xc = fminf(fmaxf(x, -20.f), 20.f);
    float t = __expf(2.f * xc);
    return (t - 1.f) * __builtin_amdgcn_rcpf(t + 1.f);
}

// Device-scope grid barrier. Counters zeroed by hipMemsetAsync each call.
// Non-waiting blocks arrive and move on. Guard cap prevents infinite hang.
__device__ __forceinline__ void gbar(unsigned* cnt, unsigned goal, bool wait) {
    __syncthreads();
    if (threadIdx.x == 0) {
        __threadfence();  // release block's writes to device scope
        __hip_atomic_fetch_add(cnt, 1u, __ATOMIC_RELEASE, __HIP_MEMORY_SCOPE_AGENT);
        if (wait) {
            int guard = 0;
            while (__hip_atomic_load(cnt, __ATOMIC_ACQUIRE, __HIP_MEMORY_SCOPE_AGENT) < goal) {
                __builtin_amdgcn_s_sleep(2);
                if (++guard > (1 << 24)) break;   // bail out rather than hang
            }
        }
    }
    __syncthreads();
    if (wait) __threadfence();  // acquire for all threads of the block
}

__global__ __launch_bounds__(256) void k_mega(
    const float* __restrict__ input, const float* __restrict__ src,
    const unsigned char* __restrict__ mask,
    const float* __restrict__ Wdec, const float* __restrict__ Wenc,
    const float* __restrict__ bias, const float* __restrict__ v,
    ushort* __restrict__ Abf, ushort* __restrict__ BTd, ushort* __restrict__ BTe,
    float* __restrict__ Cp, unsigned* __restrict__ cnt,
    float* __restrict__ out, float* __restrict__ alpha)
{
    __shared__ float t[64][65];
    const int bid = blockIdx.x;
    const int tid = threadIdx.x;

    // ================= Phase 0: convert =================
    // W transpose+cast: 512 64x64 tiles (2 matrices x 256), 2 per block
    #pragma unroll
    for (int rep = 0; rep < 2; rep++) {
        const int T = bid * 2 + rep;                  // 0..511
        const float* W = (T < 256) ? Wdec : Wenc;
        ushort* BT     = (T < 256) ? BTd : BTe;
        const int m  = T & 255;
        const int k0 = (m >> 4) * 64, n0 = (m & 15) * 64;
        if (rep) __syncthreads();                     // protect t reuse
        #pragma unroll
        for (int i = 0; i < 4; i++) {
            int idx = tid + i * 256;
            int r = idx >> 4, c4 = (idx & 15) * 4;
            float4 x = *(const float4*)(W + (size_t)(k0 + r) * DIM + n0 + c4);
            t[r][c4] = x.x; t[r][c4 + 1] = x.y; t[r][c4 + 2] = x.z; t[r][c4 + 3] = x.w;
        }
        __syncthreads();
        #pragma unroll
        for (int i = 0; i < 4; i++) {
            int idx = tid + i * 256;
            int n = idx >> 4, kc = (idx & 15) * 4;
            ushort4 o = {f2bf(t[kc][n]), f2bf(t[kc + 1][n]), f2bf(t[kc + 2][n]), f2bf(t[kc + 3][n])};
            *(ushort4*)(BT + (size_t)(n0 + n) * DIM + k0 + kc) = o;
        }
    }
    // A cast: rows 0..31 = input, rows 32..319 = first 9 s-rows of src
    #pragma unroll
    for (int i = 0; i < 2; i++) {
        int slot = i * 256 + tid;
        if (slot < 320) {
            int idx4 = bid * 320 + slot;              // 81920 float4 total
            const float* p = (idx4 < 8192) ? (input + (size_t)idx4 * 4)
                                           : (src + ((size_t)idx4 * 4 - 32768));
            float4 x = *(const float4*)p;
            ushort4 o = {f2bf(x.x), f2bf(x.y), f2bf(x.z), f2bf(x.w)};
            *(ushort4*)(Abf + (size_t)idx4 * 4) = o;
        }
    }
    // alpha one-hot (row s=8): floats [256,288) are 1
    if (tid < 64) {
        int idx4 = bid * 64 + tid;
        int f = idx4 * 4;
        float val = (f >= 256 && f < 288) ? 1.0f : 0.0f;
        float4 o = {val, val, val, val};
        *(float4*)(alpha + f) = o;
    }

    gbar(cnt, GRID, bid < 160);

    // ================= Phase 1: MFMA GEMM (640 wave-jobs) =================
    if (bid < 160) {
        const int widx = tid >> 6, lane = tid & 63;
        const int j = bid * 4 + widx;                 // 0..639
        const int kz = j & 1, tile = j >> 1;
        const int nt = tile & 31, mt = tile >> 5;     // mt 0..9 (0 = dec)
        const int r32 = lane & 31, kh = lane >> 5;
        const ushort* Ap = Abf + (size_t)(mt * 32 + r32) * DIM + kz * 512 + kh * 8;
        const ushort* Bp = ((mt == 0) ? BTd : BTe) + (size_t)(nt * 32 + r32) * DIM + kz * 512 + kh * 8;
        f32x16 acc;
        #pragma unroll
        for (int i = 0; i < 16; i++) acc[i] = 0.f;
        #pragma unroll 8
        for (int k = 0; k < 512; k += 16) {
            short8 a = *(const short8*)(Ap + k);
            short8 b = *(const short8*)(Bp + k);
            acc = __builtin_amdgcn_mfma_f32_32x32x16_bf16(a, b, acc, 0, 0, 0);
        }
        // C/D layout: col = lane&31, row = (reg&3) + 8*(reg>>2) + 4*(lane>>5)
        float* Cz = Cp + (size_t)kz * MROWS * DIM;
        #pragma unroll
        for (int r = 0; r < 16; r++) {
            int mm = (r & 3) + 8 * (r >> 2) + 4 * kh;
            Cz[(size_t)(mt * 32 + mm) * DIM + nt * 32 + r32] = acc[r];
        }
    }

    gbar(cnt + 1, GRID, bid < 32);

    // ================= Phase 2: energy + softmax + context =================
    if (bid < 32) {
        const int b = bid;
        const int h = tid * 4;
        float4 d0 = *(const float4*)(Cp + (size_t)b * DIM + h);
        float4 d1 = *(const float4*)(Cp + (size_t)(MROWS + b) * DIM + h);
        float4 bb = *(const float4*)(bias + h);
        float4 vv = *(const float4*)(v + h);
        const float bx = d0.x + d1.x + bb.x, by = d0.y + d1.y + bb.y,
                    bz = d0.z + d1.z + bb.z, bw = d0.w + d1.w + bb.w;
        float ps[PTR];
        #pragma unroll
        for (int s = 0; s < PTR; s++) {
            int row = 32 + s * 32 + b;
            float4 e0 = *(const float4*)(Cp + (size_t)row * DIM + h);
            float4 e1 = *(const float4*)(Cp + (size_t)(MROWS + row) * DIM + h);
            ps[s] = vv.x * fast_tanh(bx + e0.x + e1.x)
                  + vv.y * fast_tanh(by + e0.y + e1.y)
                  + vv.z * fast_tanh(bz + e0.z + e1.z)
                  + vv.w * fast_tanh(bw + e0.w + e1.w);
        }
        __shared__ float red[PTR][4];
        __shared__ float wgt[PTR];
        const int lane = tid & 63, wv = tid >> 6;
        #pragma unroll
        for (int s = 0; s < PTR; s++) {
            float val = ps[s];
            #pragma unroll
            for (int off = 32; off; off >>= 1) val += __shfl_down(val, off);
            if (lane == 0) red[s][wv] = val;
        }
        __syncthreads();
        if (tid == 0) {
            float es[PTR];
            float mx = -INFINITY;
            #pragma unroll
            for (int s = 0; s < PTR; s++) {
                float e = red[s][0] + red[s][1] + red[s][2] + red[s][3];
                if (mask[(size_t)s * B_SZ + b]) e = NEGINF;
                es[s] = e; mx = fmaxf(mx, e);
            }
            float tot = 0.f;
            #pragma unroll
            for (int s = 0; s < PTR; s++) { es[s] = __expf(es[s] - mx) + EPSV; tot += es[s]; }
            float inv = 1.0f / tot;
            #pragma unroll
            for (int s = 0; s < PTR; s++) wgt[s] = es[s] * inv;
        }
        __syncthreads();
        float4 acc = {0.f, 0.f, 0.f, 0.f};
        #pragma unroll
        for (int s = 0; s < PTR; s++) {
            float w = wgt[s];
            float4 x = *(const float4*)(src + (size_t)(s * B_SZ + b) * DIM + h);
            acc.x += w * x.x; acc.y += w * x.y; acc.z += w * x.z; acc.w += w * x.w;
        }
        *(float4*)(out + (size_t)b * DIM + h) = acc;
    }
}

extern "C" void kernel_launch(void* const* d_in, const int* in_sizes, int n_in,
                              void* d_out, int out_size, void* d_ws, size_t ws_size,
                              hipStream_t stream) {
    const float* input = (const float*)d_in[0];
    const float* src   = (const float*)d_in[1];
    const unsigned char* mask = (const unsigned char*)d_in[2];
    const float* Wdec  = (const float*)d_in[3];
    const float* Wenc  = (const float*)d_in[4];
    const float* bias  = (const float*)d_in[5];
    const float* v     = (const float*)d_in[6];
    float* out   = (float*)d_out;
    float* alpha = out + B_SZ * DIM;

    ushort* Abf = (ushort*)d_ws;                       // 320*1024 bf16
    ushort* BTd = Abf + (size_t)MROWS * DIM;           // 1024*1024 bf16
    ushort* BTe = BTd + (size_t)DIM * DIM;             // 1024*1024 bf16
    float*  Cp  = (float*)(BTe + (size_t)DIM * DIM);   // 2 x 320*1024 f32
    unsigned* cnt = (unsigned*)(Cp + 2 * (size_t)MROWS * DIM);  // 2 u32 counters

    hipMemsetAsync(cnt, 0, 16, stream);
    k_mega<<<dim3(GRID), 256, 0, stream>>>(input, src, mask, Wdec, Wenc, bias, v,
                                           Abf, BTd, BTe, Cp, cnt, out, alpha);
}

// Round 5
// 24.946 us; speedup vs baseline: 2.7065x; 2.7065x over previous
//
#include <hip/hip_runtime.h>
#include <hip/hip_bf16.h>
#include <math.h>

#define S_LEN 2048
#define B_SZ  32
#define DIM   1024   // D == E == H == 1024
#define PTR   9      // min((0 + 9) * 1, 2047)
#define EPSV  1e-8f
#define NEGINF -1e9f
#define MROWS 320    // 32 dec rows + 288 enc rows

typedef __attribute__((ext_vector_type(8)))  short  short8;
typedef __attribute__((ext_vector_type(16))) float  f32x16;

__device__ __forceinline__ ushort f2bf(float x) {
    __hip_bfloat16 h = __float2bfloat16(x);   // RNE
    return *(ushort*)&h;
}

__device__ __forceinline__ float fast_tanh(float x) {
    float xc = fminf(fmaxf(x, -20.f), 20.f);
    float t = __expf(2.f * xc);
    return (t - 1.f) * __builtin_amdgcn_rcpf(t + 1.f);
}

// ---------------- D1: all conversions ----------------
// W transpose+cast (both), A cast (input ++ 9 src rows), alpha one-hot.
__global__ __launch_bounds__(256) void k_convert(
    const float* __restrict__ input, const float* __restrict__ src,
    const float* __restrict__ Wdec, const float* __restrict__ Wenc,
    ushort* __restrict__ Abf, ushort* __restrict__ BTd, ushort* __restrict__ BTe,
    float* __restrict__ alpha)
{
    __shared__ float t[64][65];
    const int bid = blockIdx.x;
    const int tid = threadIdx.x;

    #pragma unroll
    for (int rep = 0; rep < 2; rep++) {
        const int T = bid * 2 + rep;                  // 0..511 tiles
        const float* W = (T < 256) ? Wdec : Wenc;
        ushort* BT     = (T < 256) ? BTd : BTe;
        const int m  = T & 255;
        const int k0 = (m >> 4) * 64, n0 = (m & 15) * 64;
        if (rep) __syncthreads();                     // protect t reuse
        #pragma unroll
        for (int i = 0; i < 4; i++) {
            int idx = tid + i * 256;
            int r = idx >> 4, c4 = (idx & 15) * 4;
            float4 x = *(const float4*)(W + (size_t)(k0 + r) * DIM + n0 + c4);
            t[r][c4] = x.x; t[r][c4 + 1] = x.y; t[r][c4 + 2] = x.z; t[r][c4 + 3] = x.w;
        }
        __syncthreads();
        #pragma unroll
        for (int i = 0; i < 4; i++) {
            int idx = tid + i * 256;
            int n = idx >> 4, kc = (idx & 15) * 4;
            ushort4 o = {f2bf(t[kc][n]), f2bf(t[kc + 1][n]), f2bf(t[kc + 2][n]), f2bf(t[kc + 3][n])};
            *(ushort4*)(BT + (size_t)(n0 + n) * DIM + k0 + kc) = o;
        }
    }
    // A cast: 81920 float4 over 256 blocks = 320 per block
    #pragma unroll
    for (int i = 0; i < 2; i++) {
        int slot = i * 256 + tid;
        if (slot < 320) {
            int idx4 = bid * 320 + slot;
            const float* p = (idx4 < 8192) ? (input + (size_t)idx4 * 4)
                                           : (src + ((size_t)idx4 * 4 - 32768));
            float4 x = *(const float4*)p;
            ushort4 o = {f2bf(x.x), f2bf(x.y), f2bf(x.z), f2bf(x.w)};
            *(ushort4*)(Abf + (size_t)idx4 * 4) = o;
        }
    }
    // alpha one-hot (row s=8): floats [256,288) = 1
    if (tid < 64) {
        int idx4 = bid * 64 + tid;
        int f = idx4 * 4;
        float val = (f >= 256 && f < 288) ? 1.0f : 0.0f;
        float4 o = {val, val, val, val};
        *(float4*)(alpha + f) = o;
    }
}

// ---------------- D2: MFMA GEMM, 4 waves/block, k-split-4 + LDS reduce ----------------
__global__ __launch_bounds__(256) void k_gemm(
    const ushort* __restrict__ Abf,
    const ushort* __restrict__ BTd,
    const ushort* __restrict__ BTe,
    float* __restrict__ C)
{
    const int nt = blockIdx.x;                   // 0..31
    const int mt = blockIdx.y;                   // 0..9 (0 = dec)
    const ushort* BT = (mt == 0) ? BTd : BTe;
    const int tid = threadIdx.x;
    const int w = tid >> 6, lane = tid & 63;
    const int r32 = lane & 31, kh = lane >> 5;
    const ushort* Ap = Abf + (size_t)(mt * 32 + r32) * DIM + w * 256 + kh * 8;
    const ushort* Bp = BT  + (size_t)(nt * 32 + r32) * DIM + w * 256 + kh * 8;

    f32x16 acc;
    #pragma unroll
    for (int i = 0; i < 16; i++) acc[i] = 0.f;
    #pragma unroll
    for (int k = 0; k < 256; k += 16) {
        short8 a = *(const short8*)(Ap + k);
        short8 b = *(const short8*)(Bp + k);
        acc = __builtin_amdgcn_mfma_f32_32x32x16_bf16(a, b, acc, 0, 0, 0);
    }
    __shared__ float red[4 * 64 * 17];
    const int base = (w * 64 + lane) * 17;
    #pragma unroll
    for (int r = 0; r < 16; r++) red[base + r] = acc[r];
    __syncthreads();
    // reduce 4 wave-copies: thread t -> lane L = t&63, regs g*4..g*4+3
    const int L = tid & 63, g = tid >> 6;
    const int khL = L >> 5, col = L & 31;
    #pragma unroll
    for (int j = 0; j < 4; j++) {
        int r = g * 4 + j;
        float s = red[(0 * 64 + L) * 17 + r] + red[(1 * 64 + L) * 17 + r]
                + red[(2 * 64 + L) * 17 + r] + red[(3 * 64 + L) * 17 + r];
        int row = (r & 3) + 8 * (r >> 2) + 4 * khL;  // C/D layout, m74/m101
        C[(size_t)(mt * 32 + row) * DIM + nt * 32 + col] = s;
    }
}

// ---------------- D3: energy + softmax + context per batch ----------------
__global__ __launch_bounds__(256) void k_tail(
    const float* __restrict__ C,
    const unsigned char* __restrict__ mask,
    const float* __restrict__ bias, const float* __restrict__ v,
    const float* __restrict__ src, float* __restrict__ out)
{
    const int b = blockIdx.x;
    const int tid = threadIdx.x;
    const int h = tid * 4;
    float4 d0 = *(const float4*)(C + (size_t)b * DIM + h);
    float4 bb = *(const float4*)(bias + h);
    float4 vv = *(const float4*)(v + h);
    const float bx = d0.x + bb.x, by = d0.y + bb.y, bz = d0.z + bb.z, bw = d0.w + bb.w;
    float ps[PTR];
    #pragma unroll
    for (int s = 0; s < PTR; s++) {
        int row = 32 + s * 32 + b;
        float4 e0 = *(const float4*)(C + (size_t)row * DIM + h);
        ps[s] = vv.x * fast_tanh(bx + e0.x) + vv.y * fast_tanh(by + e0.y)
              + vv.z * fast_tanh(bz + e0.z) + vv.w * fast_tanh(bw + e0.w);
    }
    __shared__ float red[PTR][4];
    __shared__ float wgt[PTR];
    const int lane = tid & 63, wv = tid >> 6;
    #pragma unroll
    for (int s = 0; s < PTR; s++) {
        float val = ps[s];
        #pragma unroll
        for (int off = 32; off; off >>= 1) val += __shfl_down(val, off);
        if (lane == 0) red[s][wv] = val;
    }
    __syncthreads();
    if (tid == 0) {
        float es[PTR];
        float mx = -INFINITY;
        #pragma unroll
        for (int s = 0; s < PTR; s++) {
            float e = red[s][0] + red[s][1] + red[s][2] + red[s][3];
            if (mask[(size_t)s * B_SZ + b]) e = NEGINF;
            es[s] = e; mx = fmaxf(mx, e);
        }
        float tot = 0.f;
        #pragma unroll
        for (int s = 0; s < PTR; s++) { es[s] = __expf(es[s] - mx) + EPSV; tot += es[s]; }
        float inv = 1.0f / tot;
        #pragma unroll
        for (int s = 0; s < PTR; s++) wgt[s] = es[s] * inv;
    }
    __syncthreads();
    float4 acc = {0.f, 0.f, 0.f, 0.f};
    #pragma unroll
    for (int s = 0; s < PTR; s++) {
        float wq = wgt[s];
        float4 x = *(const float4*)(src + (size_t)(s * B_SZ + b) * DIM + h);
        acc.x += wq * x.x; acc.y += wq * x.y; acc.z += wq * x.z; acc.w += wq * x.w;
    }
    *(float4*)(out + (size_t)b * DIM + h) = acc;
}

extern "C" void kernel_launch(void* const* d_in, const int* in_sizes, int n_in,
                              void* d_out, int out_size, void* d_ws, size_t ws_size,
                              hipStream_t stream) {
    const float* input = (const float*)d_in[0];
    const float* src   = (const float*)d_in[1];
    const unsigned char* mask = (const unsigned char*)d_in[2];
    const float* Wdec  = (const float*)d_in[3];
    const float* Wenc  = (const float*)d_in[4];
    const float* bias  = (const float*)d_in[5];
    const float* v     = (const float*)d_in[6];
    float* out   = (float*)d_out;
    float* alpha = out + B_SZ * DIM;

    ushort* Abf = (ushort*)d_ws;                       // 320*1024 bf16
    ushort* BTd = Abf + (size_t)MROWS * DIM;           // 1024*1024 bf16
    ushort* BTe = BTd + (size_t)DIM * DIM;             // 1024*1024 bf16
    float*  C   = (float*)(BTe + (size_t)DIM * DIM);   // 320*1024 f32

    k_convert<<<dim3(256), 256, 0, stream>>>(input, src, Wdec, Wenc, Abf, BTd, BTe, alpha);
    k_gemm<<<dim3(32, 10), 256, 0, stream>>>(Abf, BTd, BTe, C);
    k_tail<<<dim3(B_SZ), 256, 0, stream>>>(C, mask, bias, v, src, out);
}

// Round 6
// 20.869 us; speedup vs baseline: 3.2353x; 1.1954x over previous
//
#include <hip/hip_runtime.h>
#include <hip/hip_bf16.h>
#include <math.h>

#define S_LEN 2048
#define B_SZ  32
#define DIM   1024   // D == E == H == 1024
#define PTR   9      // min((0 + 9) * 1, 2047)
#define EPSV  1e-8f
#define NEGINF -1e9f
#define MROWS 320    // 32 dec rows + 288 enc rows

typedef __attribute__((ext_vector_type(8)))  short  short8;
typedef __attribute__((ext_vector_type(16))) float  f32x16;

__device__ __forceinline__ short f2bf(float x) {
    __hip_bfloat16 h = __float2bfloat16(x);   // RNE; compiler emits v_cvt_pk_bf16_f32 pairs
    return *(short*)&h;
}

__device__ __forceinline__ float fast_tanh(float x) {
    float xc = fminf(fmaxf(x, -20.f), 20.f);
    float t = __expf(2.f * xc);
    return (t - 1.f) * __builtin_amdgcn_rcpf(t + 1.f);
}

// ---------------- D1: MFMA GEMM with in-register f32->bf16 conversion ----------------
// C[mt*32+m][nt*32+n]; mt 0 = input@Wdec, mt>=1 = src rows (mt-1)*32.. @ Wenc.
// 4 waves/block, each wave a k-slice of 256, LDS reduce. Alpha one-hot folded in.
__global__ __launch_bounds__(256) void k_gemm(
    const float* __restrict__ input, const float* __restrict__ src,
    const float* __restrict__ Wdec, const float* __restrict__ Wenc,
    float* __restrict__ C, float* __restrict__ alpha)
{
    const int nt = blockIdx.x;                   // 0..31
    const int mt = blockIdx.y;                   // 0..9 (0 = dec)
    const float* W     = (mt == 0) ? Wdec : Wenc;
    const float* Abase = (mt == 0) ? input : (src + (size_t)(mt - 1) * B_SZ * DIM);
    const int tid = threadIdx.x;
    const int w = tid >> 6, lane = tid & 63;
    const int r32 = lane & 31, kh = lane >> 5;
    const float* Ap = Abase + (size_t)r32 * DIM + w * 256 + kh * 8;
    const float* Bp = W + (size_t)(w * 256 + kh * 8) * DIM + nt * 32 + r32;

    // alpha one-hot (2048x32; row s=8 -> floats [256,288) = 1), first 64 blocks
    {
        int bidl = blockIdx.y * 32 + blockIdx.x;
        if (bidl < 64) {
            int f = (bidl * 256 + tid) * 4;
            float val = (f >= 256 && f < 288) ? 1.0f : 0.0f;
            float4 o = {val, val, val, val};
            *(float4*)(alpha + f) = o;
        }
    }

    f32x16 acc;
    #pragma unroll
    for (int i = 0; i < 16; i++) acc[i] = 0.f;

    #pragma unroll 4
    for (int k = 0; k < 256; k += 16) {
        float4 a0 = *(const float4*)(Ap + k);
        float4 a1 = *(const float4*)(Ap + k + 4);
        const float* bp = Bp + (size_t)k * DIM;
        float bv0 = bp[0 * DIM], bv1 = bp[1 * DIM], bv2 = bp[2 * DIM], bv3 = bp[3 * DIM];
        float bv4 = bp[4 * DIM], bv5 = bp[5 * DIM], bv6 = bp[6 * DIM], bv7 = bp[7 * DIM];
        short8 af, bf;
        af[0] = f2bf(a0.x); af[1] = f2bf(a0.y); af[2] = f2bf(a0.z); af[3] = f2bf(a0.w);
        af[4] = f2bf(a1.x); af[5] = f2bf(a1.y); af[6] = f2bf(a1.z); af[7] = f2bf(a1.w);
        bf[0] = f2bf(bv0);  bf[1] = f2bf(bv1);  bf[2] = f2bf(bv2);  bf[3] = f2bf(bv3);
        bf[4] = f2bf(bv4);  bf[5] = f2bf(bv5);  bf[6] = f2bf(bv6);  bf[7] = f2bf(bv7);
        acc = __builtin_amdgcn_mfma_f32_32x32x16_bf16(af, bf, acc, 0, 0, 0);
    }

    __shared__ float red[4 * 64 * 17];
    const int base = (w * 64 + lane) * 17;
    #pragma unroll
    for (int r = 0; r < 16; r++) red[base + r] = acc[r];
    __syncthreads();
    // reduce the 4 k-slice copies; C/D layout: col = lane&31, row = (r&3)+8*(r>>2)+4*(lane>>5)
    const int L = tid & 63, g = tid >> 6;
    const int khL = L >> 5, col = L & 31;
    #pragma unroll
    for (int j = 0; j < 4; j++) {
        int r = g * 4 + j;
        float s = red[(0 * 64 + L) * 17 + r] + red[(1 * 64 + L) * 17 + r]
                + red[(2 * 64 + L) * 17 + r] + red[(3 * 64 + L) * 17 + r];
        int row = (r & 3) + 8 * (r >> 2) + 4 * khL;
        C[(size_t)(mt * 32 + row) * DIM + nt * 32 + col] = s;
    }
}

// ---------------- D2: energy + softmax + context per batch ----------------
__global__ __launch_bounds__(256) void k_tail(
    const float* __restrict__ C,
    const unsigned char* __restrict__ mask,
    const float* __restrict__ bias, const float* __restrict__ v,
    const float* __restrict__ src, float* __restrict__ out)
{
    const int b = blockIdx.x;
    const int tid = threadIdx.x;
    const int h = tid * 4;
    float4 d0 = *(const float4*)(C + (size_t)b * DIM + h);
    float4 bb = *(const float4*)(bias + h);
    float4 vv = *(const float4*)(v + h);
    const float bx = d0.x + bb.x, by = d0.y + bb.y, bz = d0.z + bb.z, bw = d0.w + bb.w;
    float ps[PTR];
    #pragma unroll
    for (int s = 0; s < PTR; s++) {
        int row = 32 + s * 32 + b;
        float4 e0 = *(const float4*)(C + (size_t)row * DIM + h);
        ps[s] = vv.x * fast_tanh(bx + e0.x) + vv.y * fast_tanh(by + e0.y)
              + vv.z * fast_tanh(bz + e0.z) + vv.w * fast_tanh(bw + e0.w);
    }
    __shared__ float red[PTR][4];
    __shared__ float wgt[PTR];
    const int lane = tid & 63, wv = tid >> 6;
    #pragma unroll
    for (int s = 0; s < PTR; s++) {
        float val = ps[s];
        #pragma unroll
        for (int off = 32; off; off >>= 1) val += __shfl_down(val, off);
        if (lane == 0) red[s][wv] = val;
    }
    __syncthreads();
    if (tid == 0) {
        float es[PTR];
        float mx = -INFINITY;
        #pragma unroll
        for (int s = 0; s < PTR; s++) {
            float e = red[s][0] + red[s][1] + red[s][2] + red[s][3];
            if (mask[(size_t)s * B_SZ + b]) e = NEGINF;
            es[s] = e; mx = fmaxf(mx, e);
        }
        float tot = 0.f;
        #pragma unroll
        for (int s = 0; s < PTR; s++) { es[s] = __expf(es[s] - mx) + EPSV; tot += es[s]; }
        float inv = 1.0f / tot;
        #pragma unroll
        for (int s = 0; s < PTR; s++) wgt[s] = es[s] * inv;
    }
    __syncthreads();
    float4 acc = {0.f, 0.f, 0.f, 0.f};
    #pragma unroll
    for (int s = 0; s < PTR; s++) {
        float wq = wgt[s];
        float4 x = *(const float4*)(src + (size_t)(s * B_SZ + b) * DIM + h);
        acc.x += wq * x.x; acc.y += wq * x.y; acc.z += wq * x.z; acc.w += wq * x.w;
    }
    *(float4*)(out + (size_t)b * DIM + h) = acc;
}

extern "C" void kernel_launch(void* const* d_in, const int* in_sizes, int n_in,
                              void* d_out, int out_size, void* d_ws, size_t ws_size,
                              hipStream_t stream) {
    const float* input = (const float*)d_in[0];
    const float* src   = (const float*)d_in[1];
    const unsigned char* mask = (const unsigned char*)d_in[2];
    const float* Wdec  = (const float*)d_in[3];
    const float* Wenc  = (const float*)d_in[4];
    const float* bias  = (const float*)d_in[5];
    const float* v     = (const float*)d_in[6];
    float* out   = (float*)d_out;
    float* alpha = out + B_SZ * DIM;

    float* C = (float*)d_ws;                    // 320*1024 f32

    k_gemm<<<dim3(32, 10), 256, 0, stream>>>(input, src, Wdec, Wenc, C, alpha);
    k_tail<<<dim3(B_SZ), 256, 0, stream>>>(C, mask, bias, v, src, out);
}

// Round 7
// 19.878 us; speedup vs baseline: 3.3965x; 1.0498x over previous
//
#include <hip/hip_runtime.h>
#include <hip/hip_bf16.h>
#include <math.h>

#define S_LEN 2048
#define B_SZ  32
#define DIM   1024   // D == E == H == 1024
#define PTR   9      // min((0 + 9) * 1, 2047)
#define EPSV  1e-8f
#define NEGINF -1e9f
#define MROWS 320    // 32 dec rows + 288 enc rows

typedef __attribute__((ext_vector_type(8)))  short  short8;
typedef __attribute__((ext_vector_type(16))) float  f32x16;

__device__ __forceinline__ short f2bf(float x) {
    __hip_bfloat16 h = __float2bfloat16(x);   // RNE; compiler emits v_cvt_pk_bf16_f32 pairs
    return *(short*)&h;
}

__device__ __forceinline__ float fast_tanh(float x) {
    float xc = fminf(fmaxf(x, -20.f), 20.f);
    float t = __expf(2.f * xc);
    return (t - 1.f) * __builtin_amdgcn_rcpf(t + 1.f);
}

// ---------------- D1: MFMA GEMM, in-register f32->bf16, k-split over blocks ----------------
// Grid (32 nt, 10 mt, 2 kz). Block computes partial C_kz[mt*32+m][nt*32+n] over K=512,
// 4 waves x K=128 each, LDS reduce. Alpha one-hot folded into kz==0 blocks.
__global__ __launch_bounds__(256) void k_gemm(
    const float* __restrict__ input, const float* __restrict__ src,
    const float* __restrict__ Wdec, const float* __restrict__ Wenc,
    float* __restrict__ Cp, float* __restrict__ alpha)
{
    const int nt = blockIdx.x;                   // 0..31
    const int mt = blockIdx.y;                   // 0..9 (0 = dec)
    const int kz = blockIdx.z;                   // 0..1
    const float* W     = (mt == 0) ? Wdec : Wenc;
    const float* Abase = (mt == 0) ? input : (src + (size_t)(mt - 1) * B_SZ * DIM);
    const int tid = threadIdx.x;
    const int w = tid >> 6, lane = tid & 63;
    const int r32 = lane & 31, kh = lane >> 5;
    const int kbase = kz * 512 + w * 128;
    const float* Ap = Abase + (size_t)r32 * DIM + kbase + kh * 8;
    const float* Bp = W + (size_t)(kbase + kh * 8) * DIM + nt * 32 + r32;

    // alpha one-hot (2048x32; row s=8 -> floats [256,288) = 1), 64 blocks of kz==0
    if (kz == 0) {
        int bidl = mt * 32 + nt;
        if (bidl < 64) {
            int f = (bidl * 256 + tid) * 4;
            float val = (f >= 256 && f < 288) ? 1.0f : 0.0f;
            float4 o = {val, val, val, val};
            *(float4*)(alpha + f) = o;
        }
    }

    f32x16 acc;
    #pragma unroll
    for (int i = 0; i < 16; i++) acc[i] = 0.f;

    #pragma unroll 4
    for (int k = 0; k < 128; k += 16) {
        float4 a0 = *(const float4*)(Ap + k);
        float4 a1 = *(const float4*)(Ap + k + 4);
        const float* bp = Bp + (size_t)k * DIM;
        float bv0 = bp[0 * DIM], bv1 = bp[1 * DIM], bv2 = bp[2 * DIM], bv3 = bp[3 * DIM];
        float bv4 = bp[4 * DIM], bv5 = bp[5 * DIM], bv6 = bp[6 * DIM], bv7 = bp[7 * DIM];
        short8 af, bf;
        af[0] = f2bf(a0.x); af[1] = f2bf(a0.y); af[2] = f2bf(a0.z); af[3] = f2bf(a0.w);
        af[4] = f2bf(a1.x); af[5] = f2bf(a1.y); af[6] = f2bf(a1.z); af[7] = f2bf(a1.w);
        bf[0] = f2bf(bv0);  bf[1] = f2bf(bv1);  bf[2] = f2bf(bv2);  bf[3] = f2bf(bv3);
        bf[4] = f2bf(bv4);  bf[5] = f2bf(bv5);  bf[6] = f2bf(bv6);  bf[7] = f2bf(bv7);
        acc = __builtin_amdgcn_mfma_f32_32x32x16_bf16(af, bf, acc, 0, 0, 0);
    }

    __shared__ float red[4 * 64 * 17];
    const int base = (w * 64 + lane) * 17;
    #pragma unroll
    for (int r = 0; r < 16; r++) red[base + r] = acc[r];
    __syncthreads();
    // reduce the 4 wave k-slices; C/D layout: col = lane&31, row = (r&3)+8*(r>>2)+4*(lane>>5)
    const int L = tid & 63, g = tid >> 6;
    const int khL = L >> 5, col = L & 31;
    float* Cz = Cp + (size_t)kz * MROWS * DIM;
    #pragma unroll
    for (int j = 0; j < 4; j++) {
        int r = g * 4 + j;
        float s = red[(0 * 64 + L) * 17 + r] + red[(1 * 64 + L) * 17 + r]
                + red[(2 * 64 + L) * 17 + r] + red[(3 * 64 + L) * 17 + r];
        int row = (r & 3) + 8 * (r >> 2) + 4 * khL;
        Cz[(size_t)(mt * 32 + row) * DIM + nt * 32 + col] = s;
    }
}

// ---------------- D2: energy + softmax + context per batch ----------------
__global__ __launch_bounds__(256) void k_tail(
    const float* __restrict__ Cp,
    const unsigned char* __restrict__ mask,
    const float* __restrict__ bias, const float* __restrict__ v,
    const float* __restrict__ src, float* __restrict__ out)
{
    const int b = blockIdx.x;
    const int tid = threadIdx.x;
    const int h = tid * 4;
    const float* C0 = Cp;
    const float* C1 = Cp + (size_t)MROWS * DIM;

    // hoisted src loads: independent of C, hide HBM latency under energy phase
    float4 sv[PTR];
    #pragma unroll
    for (int s = 0; s < PTR; s++)
        sv[s] = *(const float4*)(src + (size_t)(s * B_SZ + b) * DIM + h);

    float4 da = *(const float4*)(C0 + (size_t)b * DIM + h);
    float4 db = *(const float4*)(C1 + (size_t)b * DIM + h);
    float4 bb = *(const float4*)(bias + h);
    float4 vv = *(const float4*)(v + h);
    const float bx = da.x + db.x + bb.x, by = da.y + db.y + bb.y,
                bz = da.z + db.z + bb.z, bw = da.w + db.w + bb.w;
    float ps[PTR];
    #pragma unroll
    for (int s = 0; s < PTR; s++) {
        int row = 32 + s * 32 + b;
        float4 e0 = *(const float4*)(C0 + (size_t)row * DIM + h);
        float4 e1 = *(const float4*)(C1 + (size_t)row * DIM + h);
        ps[s] = vv.x * fast_tanh(bx + e0.x + e1.x) + vv.y * fast_tanh(by + e0.y + e1.y)
              + vv.z * fast_tanh(bz + e0.z + e1.z) + vv.w * fast_tanh(bw + e0.w + e1.w);
    }
    __shared__ float red[PTR][4];
    __shared__ float wgt[PTR];
    const int lane = tid & 63, wv = tid >> 6;
    #pragma unroll
    for (int s = 0; s < PTR; s++) {
        float val = ps[s];
        #pragma unroll
        for (int off = 32; off; off >>= 1) val += __shfl_down(val, off);
        if (lane == 0) red[s][wv] = val;
    }
    __syncthreads();
    if (tid == 0) {
        float es[PTR];
        float mx = -INFINITY;
        #pragma unroll
        for (int s = 0; s < PTR; s++) {
            float e = red[s][0] + red[s][1] + red[s][2] + red[s][3];
            if (mask[(size_t)s * B_SZ + b]) e = NEGINF;
            es[s] = e; mx = fmaxf(mx, e);
        }
        float tot = 0.f;
        #pragma unroll
        for (int s = 0; s < PTR; s++) { es[s] = __expf(es[s] - mx) + EPSV; tot += es[s]; }
        float inv = 1.0f / tot;
        #pragma unroll
        for (int s = 0; s < PTR; s++) wgt[s] = es[s] * inv;
    }
    __syncthreads();
    float4 acc = {0.f, 0.f, 0.f, 0.f};
    #pragma unroll
    for (int s = 0; s < PTR; s++) {
        float wq = wgt[s];
        acc.x += wq * sv[s].x; acc.y += wq * sv[s].y;
        acc.z += wq * sv[s].z; acc.w += wq * sv[s].w;
    }
    *(float4*)(out + (size_t)b * DIM + h) = acc;
}

extern "C" void kernel_launch(void* const* d_in, const int* in_sizes, int n_in,
                              void* d_out, int out_size, void* d_ws, size_t ws_size,
                              hipStream_t stream) {
    const float* input = (const float*)d_in[0];
    const float* src   = (const float*)d_in[1];
    const unsigned char* mask = (const unsigned char*)d_in[2];
    const float* Wdec  = (const float*)d_in[3];
    const float* Wenc  = (const float*)d_in[4];
    const float* bias  = (const float*)d_in[5];
    const float* v     = (const float*)d_in[6];
    float* out   = (float*)d_out;
    float* alpha = out + B_SZ * DIM;

    float* Cp = (float*)d_ws;                   // 2 x 320*1024 f32 partials

    k_gemm<<<dim3(32, 10, 2), 256, 0, stream>>>(input, src, Wdec, Wenc, Cp, alpha);
    k_tail<<<dim3(B_SZ), 256, 0, stream>>>(Cp, mask, bias, v, src, out);
}

// Round 8
// 19.760 us; speedup vs baseline: 3.4168x; 1.0060x over previous
//
#include <hip/hip_runtime.h>
#include <hip/hip_bf16.h>
#include <math.h>

#define S_LEN 2048
#define B_SZ  32
#define DIM   1024   // D == E == H == 1024
#define PTR   9      // min((0 + 9) * 1, 2047)
#define EPSV  1e-8f
#define NEGINF -1e9f
#define MROWS 320    // 32 dec rows + 288 enc rows

typedef __attribute__((ext_vector_type(8)))  short  short8;
typedef __attribute__((ext_vector_type(16))) float  f32x16;

__device__ __forceinline__ short f2bf(float x) {
    __hip_bfloat16 h = __float2bfloat16(x);   // RNE; compiler emits v_cvt_pk_bf16_f32 pairs
    return *(short*)&h;
}

__device__ __forceinline__ float fast_tanh(float x) {
    float xc = fminf(fmaxf(x, -20.f), 20.f);
    float t = __expf(2.f * xc);
    return (t - 1.f) * __builtin_amdgcn_rcpf(t + 1.f);
}

// ---------------- D1: MFMA GEMM, in-register f32->bf16, k-split over blocks ----------------
// Grid (32 nt, 10 mt, 2 kz). Block computes partial C_kz[mt*32+m][nt*32+n] over K=512,
// 4 waves x K=128 each, LDS reduce. Alpha one-hot folded into kz==0 blocks.
__global__ __launch_bounds__(256) void k_gemm(
    const float* __restrict__ input, const float* __restrict__ src,
    const float* __restrict__ Wdec, const float* __restrict__ Wenc,
    float* __restrict__ Cp, float* __restrict__ alpha)
{
    const int nt = blockIdx.x;                   // 0..31
    const int mt = blockIdx.y;                   // 0..9 (0 = dec)
    const int kz = blockIdx.z;                   // 0..1
    const float* W     = (mt == 0) ? Wdec : Wenc;
    const float* Abase = (mt == 0) ? input : (src + (size_t)(mt - 1) * B_SZ * DIM);
    const int tid = threadIdx.x;
    const int w = tid >> 6, lane = tid & 63;
    const int r32 = lane & 31, kh = lane >> 5;
    const int kbase = kz * 512 + w * 128;
    const float* Ap = Abase + (size_t)r32 * DIM + kbase + kh * 8;
    const float* Bp = W + (size_t)(kbase + kh * 8) * DIM + nt * 32 + r32;

    // alpha one-hot (2048x32; row s=8 -> floats [256,288) = 1), 64 blocks of kz==0
    if (kz == 0) {
        int bidl = mt * 32 + nt;
        if (bidl < 64) {
            int f = (bidl * 256 + tid) * 4;
            float val = (f >= 256 && f < 288) ? 1.0f : 0.0f;
            float4 o = {val, val, val, val};
            *(float4*)(alpha + f) = o;
        }
    }

    f32x16 acc;
    #pragma unroll
    for (int i = 0; i < 16; i++) acc[i] = 0.f;

    #pragma unroll 4
    for (int k = 0; k < 128; k += 16) {
        float4 a0 = *(const float4*)(Ap + k);
        float4 a1 = *(const float4*)(Ap + k + 4);
        const float* bp = Bp + (size_t)k * DIM;
        float bv0 = bp[0 * DIM], bv1 = bp[1 * DIM], bv2 = bp[2 * DIM], bv3 = bp[3 * DIM];
        float bv4 = bp[4 * DIM], bv5 = bp[5 * DIM], bv6 = bp[6 * DIM], bv7 = bp[7 * DIM];
        short8 af, bf;
        af[0] = f2bf(a0.x); af[1] = f2bf(a0.y); af[2] = f2bf(a0.z); af[3] = f2bf(a0.w);
        af[4] = f2bf(a1.x); af[5] = f2bf(a1.y); af[6] = f2bf(a1.z); af[7] = f2bf(a1.w);
        bf[0] = f2bf(bv0);  bf[1] = f2bf(bv1);  bf[2] = f2bf(bv2);  bf[3] = f2bf(bv3);
        bf[4] = f2bf(bv4);  bf[5] = f2bf(bv5);  bf[6] = f2bf(bv6);  bf[7] = f2bf(bv7);
        acc = __builtin_amdgcn_mfma_f32_32x32x16_bf16(af, bf, acc, 0, 0, 0);
    }

    __shared__ float red[4 * 64 * 17];
    const int base = (w * 64 + lane) * 17;
    #pragma unroll
    for (int r = 0; r < 16; r++) red[base + r] = acc[r];
    __syncthreads();
    // reduce the 4 wave k-slices; C/D layout: col = lane&31, row = (r&3)+8*(r>>2)+4*(lane>>5)
    const int L = tid & 63, g = tid >> 6;
    const int khL = L >> 5, col = L & 31;
    float* Cz = Cp + (size_t)kz * MROWS * DIM;
    #pragma unroll
    for (int j = 0; j < 4; j++) {
        int r = g * 4 + j;
        float s = red[(0 * 64 + L) * 17 + r] + red[(1 * 64 + L) * 17 + r]
                + red[(2 * 64 + L) * 17 + r] + red[(3 * 64 + L) * 17 + r];
        int row = (r & 3) + 8 * (r >> 2) + 4 * khL;
        Cz[(size_t)(mt * 32 + row) * DIM + nt * 32 + col] = s;
    }
}

// ---------------- D2: energy (redundant per h-slice) + softmax + sliced context ----------------
// Grid (32 b, 8 hs). Each block computes full-H energy+softmax for its b (L2-shared
// C rows), then writes context only for its 128-float h-slice.
__global__ __launch_bounds__(256) void k_tail(
    const float* __restrict__ Cp,
    const unsigned char* __restrict__ mask,
    const float* __restrict__ bias, const float* __restrict__ v,
    const float* __restrict__ src, float* __restrict__ out)
{
    const int b  = blockIdx.x;                 // 0..31
    const int hs = blockIdx.y;                 // 0..7
    const int tid = threadIdx.x;
    const int h = tid * 4;
    const float* C0 = Cp;
    const float* C1 = Cp + (size_t)MROWS * DIM;

    // hoisted src loads for this block's context slice (independent of C)
    const int hc = hs * 128 + (tid & 31) * 4;
    float4 sv[PTR];
    #pragma unroll
    for (int s = 0; s < PTR; s++)
        sv[s] = *(const float4*)(src + (size_t)(s * B_SZ + b) * DIM + hc);

    float4 da = *(const float4*)(C0 + (size_t)b * DIM + h);
    float4 db = *(const float4*)(C1 + (size_t)b * DIM + h);
    float4 bb = *(const float4*)(bias + h);
    float4 vv = *(const float4*)(v + h);
    const float bx = da.x + db.x + bb.x, by = da.y + db.y + bb.y,
                bz = da.z + db.z + bb.z, bw = da.w + db.w + bb.w;
    float ps[PTR];
    #pragma unroll
    for (int s = 0; s < PTR; s++) {
        int row = 32 + s * 32 + b;
        float4 e0 = *(const float4*)(C0 + (size_t)row * DIM + h);
        float4 e1 = *(const float4*)(C1 + (size_t)row * DIM + h);
        ps[s] = vv.x * fast_tanh(bx + e0.x + e1.x) + vv.y * fast_tanh(by + e0.y + e1.y)
              + vv.z * fast_tanh(bz + e0.z + e1.z) + vv.w * fast_tanh(bw + e0.w + e1.w);
    }
    __shared__ float red[PTR][4];
    __shared__ float wgt[PTR];
    const int lane = tid & 63, wv = tid >> 6;
    #pragma unroll
    for (int s = 0; s < PTR; s++) {
        float val = ps[s];
        #pragma unroll
        for (int off = 32; off; off >>= 1) val += __shfl_down(val, off);
        if (lane == 0) red[s][wv] = val;
    }
    __syncthreads();
    if (tid == 0) {
        float es[PTR];
        float mx = -INFINITY;
        #pragma unroll
        for (int s = 0; s < PTR; s++) {
            float e = red[s][0] + red[s][1] + red[s][2] + red[s][3];
            if (mask[(size_t)s * B_SZ + b]) e = NEGINF;
            es[s] = e; mx = fmaxf(mx, e);
        }
        float tot = 0.f;
        #pragma unroll
        for (int s = 0; s < PTR; s++) { es[s] = __expf(es[s] - mx) + EPSV; tot += es[s]; }
        float inv = 1.0f / tot;
        #pragma unroll
        for (int s = 0; s < PTR; s++) wgt[s] = es[s] * inv;
    }
    __syncthreads();
    if (tid < 32) {
        float4 acc = {0.f, 0.f, 0.f, 0.f};
        #pragma unroll
        for (int s = 0; s < PTR; s++) {
            float wq = wgt[s];
            acc.x += wq * sv[s].x; acc.y += wq * sv[s].y;
            acc.z += wq * sv[s].z; acc.w += wq * sv[s].w;
        }
        *(float4*)(out + (size_t)b * DIM + hc) = acc;
    }
}

extern "C" void kernel_launch(void* const* d_in, const int* in_sizes, int n_in,
                              void* d_out, int out_size, void* d_ws, size_t ws_size,
                              hipStream_t stream) {
    const float* input = (const float*)d_in[0];
    const float* src   = (const float*)d_in[1];
    const unsigned char* mask = (const unsigned char*)d_in[2];
    const float* Wdec  = (const float*)d_in[3];
    const float* Wenc  = (const float*)d_in[4];
    const float* bias  = (const float*)d_in[5];
    const float* v     = (const float*)d_in[6];
    float* out   = (float*)d_out;
    float* alpha = out + B_SZ * DIM;

    float* Cp = (float*)d_ws;                   // 2 x 320*1024 f32 partials

    k_gemm<<<dim3(32, 10, 2), 256, 0, stream>>>(input, src, Wdec, Wenc, Cp, alpha);
    k_tail<<<dim3(B_SZ, 8), 256, 0, stream>>>(Cp, mask, bias, v, src, out);
}